// Round 2
// baseline (162.942 us; speedup 1.0000x reference)
//
#include <hip/hip_runtime.h>
#include <stdint.h>

// Problem: B=32, S=2048, E2=1024, D=512
//   c[b][d]    = b_att[d] + sum_k dec[b][k] * W_att[1024+k][d]
//   att[b][s]  = sum_d tanh( sum_e x[b][s][e]*W_att[e][d] + c[b][d] ) * v[d]
//   w          = softmax(att, axis=s)
//   out[b][e]  = sum_s w[b][s] * x[b][s][e]
//
// ws layout: [0,256K) attention f32[65536]; [256K,320K) cbias f32[16384];
//            [320K, 320K+1MiB) W_enc bf16, pre-swizzled per 64-k chunk.

typedef __attribute__((ext_vector_type(8))) __bf16 bf16x8;
typedef __attribute__((ext_vector_type(4))) float f32x4;

__device__ __forceinline__ uint16_t f32_to_bf16_rne(float f) {
  union { float f; uint32_t u; } v; v.f = f;
  uint32_t u = v.u;
  return (uint16_t)((u + 0x7FFFu + ((u >> 16) & 1u)) >> 16);
}

__device__ __forceinline__ float tanh_fast(float x) {
  float e = __expf(2.0f * x);
  return 1.0f - 2.0f * __builtin_amdgcn_rcpf(e + 1.0f);
}

// ---------------- Kernel A: prep (unchanged from round 1) ----------------
__global__ __launch_bounds__(256) void prep_kernel(
    const float* __restrict__ dec,   // (32,512)
    const float* __restrict__ Watt,  // (1536,512)
    const float* __restrict__ batt,  // (512)
    float* __restrict__ att,         // ws (65536)
    float* __restrict__ cbias,       // ws (32*512)
    uint16_t* __restrict__ Wb,       // ws (1024*512 bf16, swizzled)
    float* __restrict__ out)         // d_out (32768) -> zero
{
  const int t = blockIdx.x * 256 + threadIdx.x;  // [0,16384)

  for (int i = t; i < 65536; i += 16384) att[i] = 0.0f;
  for (int i = t; i < 32768; i += 16384) out[i] = 0.0f;

  {
    const int b = t >> 9, d = t & 511;
    const float* wd = Watt + 1024 * 512 + d;
    const float* dv = dec + b * 512;
    float s0 = 0.f, s1 = 0.f, s2 = 0.f, s3 = 0.f;
    #pragma unroll 4
    for (int k = 0; k < 512; k += 4) {
      s0 += dv[k + 0] * wd[(k + 0) * 512];
      s1 += dv[k + 1] * wd[(k + 1) * 512];
      s2 += dv[k + 2] * wd[(k + 2) * 512];
      s3 += dv[k + 3] * wd[(k + 3) * 512];
    }
    cbias[t] = batt[d] + ((s0 + s1) + (s2 + s3));
  }

  // W_enc -> bf16, global image == energy kernel's LDS image (linear copy):
  // chunk c: 16B unit (d, j) at byte d*128 + ((j*16) ^ ((d&7)<<4)),
  // holding W_enc[64c+8j+i][d], i=0..7.
  uint4* WbV = (uint4*)Wb;
  #pragma unroll
  for (int i = 0; i < 4; ++i) {
    const int u = t + 16384 * i;       // [0,65536)
    const int d = u & 511;
    const int j = (u >> 9) & 7;
    const int c = u >> 12;
    uint32_t h[8];
    #pragma unroll
    for (int kk = 0; kk < 8; ++kk) {
      float f = Watt[(size_t)(c * 64 + j * 8 + kk) * 512 + d];
      h[kk] = f32_to_bf16_rne(f);
    }
    uint4 val;
    val.x = h[0] | (h[1] << 16);
    val.y = h[2] | (h[3] << 16);
    val.z = h[4] | (h[5] << 16);
    val.w = h[6] | (h[7] << 16);
    const int unit = (d * 128 + ((j * 16) ^ ((d & 7) << 4))) >> 4;
    WbV[c * 4096 + unit] = val;
  }
}

// ---------------- Kernel B: fused energy GEMM + tanh + dot(v), v2 ----------------
// 512 blocks x 512 threads (8 waves, 2x4). BM=128, BN=512 (full), BK=64.
// Double-buffered A (reg-staged f32->bf16) and B (global_load_lds from
// pre-swizzled image); ONE barrier per chunk; loads issued a full compute
// phase before their consuming barrier.
__global__ __launch_bounds__(512, 2) void energy_kernel(
    const float* __restrict__ x,       // (65536,1024)
    const uint16_t* __restrict__ Wb,   // swizzled bf16 chunks (1 MiB)
    const float* __restrict__ cbias,   // (32,512)
    const float* __restrict__ vvec,    // (512)
    float* __restrict__ att)           // (65536), pre-zeroed
{
  __shared__ __align__(16) uint8_t AL[2][128 * 128];   // 2 x 16 KB : A 128r x 64k bf16
  __shared__ __align__(16) uint8_t BL[2][512 * 128];   // 2 x 64 KB : B 512d x 64k bf16

  const int tid  = threadIdx.x;
  const int lane = tid & 63;
  const int wave = tid >> 6;
  const int wm   = wave >> 2;          // 0..1  (64-row group)
  const int wn   = wave & 3;           // 0..3  (128-col group)
  const int l15  = lane & 15;
  const int l4   = lane >> 4;
  const int brow0 = blockIdx.x * 128;
  const int b     = brow0 >> 11;

  // A staging map: 4 units/thread of 8B (4 bf16 from one float4)
  int aoff[4];
  const float* asrc[4];
  #pragma unroll
  for (int i = 0; i < 4; ++i) {
    const int idx = tid + 512 * i;     // [0,2048)
    const int r = idx >> 4, q = idx & 15;
    aoff[i] = r * 128 + ((q * 8) ^ ((r & 7) << 4));
    asrc[i] = x + (size_t)(brow0 + r) * 1024 + q * 4;
  }
  const uint8_t* wbase = (const uint8_t*)Wb + (lane << 4);

  f32x4 acc[4][8];
  #pragma unroll
  for (int mf = 0; mf < 4; ++mf)
    #pragma unroll
    for (int nf = 0; nf < 8; ++nf)
      acc[mf][nf] = (f32x4){0.f, 0.f, 0.f, 0.f};

  // prologue: issue A(0) reg loads + B(0) global_load_lds
  float4 av[4];
  #pragma unroll
  for (int i = 0; i < 4; ++i) av[i] = *(const float4*)(asrc[i]);
  #pragma unroll
  for (int i = 0; i < 8; ++i) {
    const int u = i * 8 + wave;
    __builtin_amdgcn_global_load_lds(
        (const __attribute__((address_space(1))) uint32_t*)(wbase + u * 1024),
        (__attribute__((address_space(3))) uint32_t*)(&BL[0][u * 1024]),
        16, 0, 0);
  }

  for (int c = 0; c < 16; ++c) {
    uint8_t* Ab = AL[c & 1];
    uint8_t* Bb = BL[c & 1];

    // cvt + swizzled write A(c). Safe: all waves passed barrier(c-1) =>
    // finished compute(c-2) which read AL[c&1].
    #pragma unroll
    for (int i = 0; i < 4; ++i) {
      uint32_t lo = (uint32_t)f32_to_bf16_rne(av[i].x) | ((uint32_t)f32_to_bf16_rne(av[i].y) << 16);
      uint32_t hi = (uint32_t)f32_to_bf16_rne(av[i].z) | ((uint32_t)f32_to_bf16_rne(av[i].w) << 16);
      *(uint2*)(Ab + aoff[i]) = make_uint2(lo, hi);
    }

    __syncthreads();  // vmcnt(0): B(c) arrived (issued a full phase ago); lgkm: A visible

    if (c < 15) {
      // issue B(c+1): safe, everyone finished compute(c-1) which read BL[(c+1)&1]
      const uint8_t* wc = wbase + ((size_t)(c + 1) << 16);
      uint8_t* Bn = BL[(c + 1) & 1];
      #pragma unroll
      for (int i = 0; i < 8; ++i) {
        const int u = i * 8 + wave;
        __builtin_amdgcn_global_load_lds(
            (const __attribute__((address_space(1))) uint32_t*)(wc + u * 1024),
            (__attribute__((address_space(3))) uint32_t*)(Bn + u * 1024),
            16, 0, 0);
      }
      // issue A(c+1) reg loads (HBM latency hides under compute(c))
      #pragma unroll
      for (int i = 0; i < 4; ++i) av[i] = *(const float4*)(asrc[i] + (c + 1) * 64);
    }

    // compute chunk c
    #pragma unroll
    for (int ks = 0; ks < 2; ++ks) {
      bf16x8 af[4], bfr[8];
      #pragma unroll
      for (int mf = 0; mf < 4; ++mf) {
        const int r = wm * 64 + mf * 16 + l15;
        af[mf] = *(const bf16x8*)(Ab + r * 128 + ((ks * 64 + l4 * 16) ^ ((r & 7) << 4)));
      }
      #pragma unroll
      for (int nf = 0; nf < 8; ++nf) {
        const int d = wn * 128 + nf * 16 + l15;
        bfr[nf] = *(const bf16x8*)(Bb + d * 128 + ((ks * 64 + l4 * 16) ^ ((d & 7) << 4)));
      }
      #pragma unroll
      for (int mf = 0; mf < 4; ++mf)
        #pragma unroll
        for (int nf = 0; nf < 8; ++nf)
          acc[mf][nf] = __builtin_amdgcn_mfma_f32_16x16x32_bf16(af[mf], bfr[nf], acc[mf][nf], 0, 0, 0);
    }
  }

  // epilogue: tanh + dot(v), 16-lane reduce, one atomic per (row, wn)
  float cb[8], vv[8];
  #pragma unroll
  for (int nf = 0; nf < 8; ++nf) {
    const int d = wn * 128 + nf * 16 + l15;
    cb[nf] = cbias[b * 512 + d];
    vv[nf] = vvec[d];
  }
  #pragma unroll
  for (int mf = 0; mf < 4; ++mf) {
    float s[4] = {0.f, 0.f, 0.f, 0.f};
    #pragma unroll
    for (int nf = 0; nf < 8; ++nf) {
      #pragma unroll
      for (int j = 0; j < 4; ++j) {
        const float e = acc[mf][nf][j] + cb[nf];
        s[j] += tanh_fast(e) * vv[nf];
      }
    }
    #pragma unroll
    for (int j = 0; j < 4; ++j) {
      float r = s[j];
      r += __shfl_xor(r, 1);
      r += __shfl_xor(r, 2);
      r += __shfl_xor(r, 4);
      r += __shfl_xor(r, 8);
      if (l15 == 0) atomicAdd(&att[brow0 + wm * 64 + mf * 16 + 4 * l4 + j], r);
    }
  }
}

// ---------------- Kernel C: softmax over S (in place) ----------------
__global__ __launch_bounds__(256) void softmax_kernel(float* __restrict__ att) {
  const int b = blockIdx.x;
  float* row = att + b * 2048;
  const int tid = threadIdx.x;
  __shared__ float redm[4], reds[4];

  float vals[8];
  float m = -1e30f;
  #pragma unroll
  for (int i = 0; i < 8; ++i) { vals[i] = row[tid + 256 * i]; m = fmaxf(m, vals[i]); }
  #pragma unroll
  for (int msk = 1; msk < 64; msk <<= 1) m = fmaxf(m, __shfl_xor(m, msk));
  if ((tid & 63) == 0) redm[tid >> 6] = m;
  __syncthreads();
  m = fmaxf(fmaxf(redm[0], redm[1]), fmaxf(redm[2], redm[3]));

  float s = 0.f;
  #pragma unroll
  for (int i = 0; i < 8; ++i) { vals[i] = __expf(vals[i] - m); s += vals[i]; }
  #pragma unroll
  for (int msk = 1; msk < 64; msk <<= 1) s += __shfl_xor(s, msk);
  if ((tid & 63) == 0) reds[tid >> 6] = s;
  __syncthreads();
  const float inv = 1.0f / (((reds[0] + reds[1]) + (reds[2] + reds[3])));
  #pragma unroll
  for (int i = 0; i < 8; ++i) row[tid + 256 * i] = vals[i] * inv;
}

// ---------------- Kernel D: context = w @ x ----------------
__global__ __launch_bounds__(256) void context_kernel(
    const float* __restrict__ x,   // (65536,1024)
    const float* __restrict__ w,   // (32,2048)
    float* __restrict__ out)       // (32,1024), pre-zeroed
{
  const int blk = blockIdx.x;
  const int b = blk >> 4, sc = blk & 15;
  const int tid = threadIdx.x;
  const float* xb = x + ((size_t)(b * 2048 + sc * 128)) * 1024 + tid * 4;
  const float* wb = w + b * 2048 + sc * 128;

  float4 acc = {0.f, 0.f, 0.f, 0.f};
  for (int si = 0; si < 128; ++si) {
    const float ww = wb[si];
    const float4 xv = *(const float4*)(xb + (size_t)si * 1024);
    acc.x += ww * xv.x;
    acc.y += ww * xv.y;
    acc.z += ww * xv.z;
    acc.w += ww * xv.w;
  }
  float* o = out + b * 1024 + tid * 4;
  atomicAdd(o + 0, acc.x);
  atomicAdd(o + 1, acc.y);
  atomicAdd(o + 2, acc.z);
  atomicAdd(o + 3, acc.w);
}

extern "C" void kernel_launch(void* const* d_in, const int* in_sizes, int n_in,
                              void* d_out, int out_size, void* d_ws, size_t ws_size,
                              hipStream_t stream) {
  const float* x    = (const float*)d_in[0];  // (32,2048,1024)
  const float* dec  = (const float*)d_in[1];  // (32,512)
  const float* Watt = (const float*)d_in[2];  // (1536,512)
  const float* batt = (const float*)d_in[3];  // (512)
  const float* v    = (const float*)d_in[4];  // (512)
  float* out = (float*)d_out;

  uint8_t* ws = (uint8_t*)d_ws;
  float*    att   = (float*)ws;                        // 256 KB
  float*    cbias = (float*)(ws + 256 * 1024);         // 64 KB
  uint16_t* Wb    = (uint16_t*)(ws + 320 * 1024);      // 1 MiB

  prep_kernel<<<64, 256, 0, stream>>>(dec, Watt, batt, att, cbias, Wb, out);
  energy_kernel<<<512, 512, 0, stream>>>(x, Wb, cbias, v, att);
  softmax_kernel<<<32, 256, 0, stream>>>(att);
  context_kernel<<<512, 256, 0, stream>>>(x, att, out);
}

// Round 3
// 159.865 us; speedup vs baseline: 1.0192x; 1.0192x over previous
//
#include <hip/hip_runtime.h>
#include <stdint.h>

// Problem: B=32, S=2048, E2=1024, D=512
//   c[b][d]    = b_att[d] + sum_k dec[b][k] * W_att[1024+k][d]
//   att[b][s]  = sum_d tanh( sum_e x[b][s][e]*W_att[e][d] + c[b][d] ) * v[d]
//   w          = softmax(att, axis=s)
//   out[b][e]  = sum_s w[b][s] * x[b][s][e]
//
// ws layout: [0,256K) attention f32[65536]; [256K,320K) cbias f32[16384];
//            [320K, 320K+1MiB) W_enc bf16, pre-swizzled per 64-k chunk.

typedef __attribute__((ext_vector_type(8))) __bf16 bf16x8;
typedef __attribute__((ext_vector_type(4))) float f32x4;

__device__ __forceinline__ uint16_t f32_to_bf16_rne(float f) {
  union { float f; uint32_t u; } v; v.f = f;
  uint32_t u = v.u;
  return (uint16_t)((u + 0x7FFFu + ((u >> 16) & 1u)) >> 16);
}

__device__ __forceinline__ float tanh_fast(float x) {
  float e = __expf(2.0f * x);
  return 1.0f - 2.0f * __builtin_amdgcn_rcpf(e + 1.0f);
}

// ---------------- Kernel A: prep (unchanged) ----------------
__global__ __launch_bounds__(256) void prep_kernel(
    const float* __restrict__ dec,   // (32,512)
    const float* __restrict__ Watt,  // (1536,512)
    const float* __restrict__ batt,  // (512)
    float* __restrict__ att,         // ws (65536)
    float* __restrict__ cbias,       // ws (32*512)
    uint16_t* __restrict__ Wb,       // ws (1024*512 bf16, swizzled)
    float* __restrict__ out)         // d_out (32768) -> zero
{
  const int t = blockIdx.x * 256 + threadIdx.x;  // [0,16384)

  for (int i = t; i < 65536; i += 16384) att[i] = 0.0f;
  for (int i = t; i < 32768; i += 16384) out[i] = 0.0f;

  {
    const int b = t >> 9, d = t & 511;
    const float* wd = Watt + 1024 * 512 + d;
    const float* dv = dec + b * 512;
    float s0 = 0.f, s1 = 0.f, s2 = 0.f, s3 = 0.f;
    #pragma unroll 4
    for (int k = 0; k < 512; k += 4) {
      s0 += dv[k + 0] * wd[(k + 0) * 512];
      s1 += dv[k + 1] * wd[(k + 1) * 512];
      s2 += dv[k + 2] * wd[(k + 2) * 512];
      s3 += dv[k + 3] * wd[(k + 3) * 512];
    }
    cbias[t] = batt[d] + ((s0 + s1) + (s2 + s3));
  }

  // W_enc -> bf16, global image == energy kernel's LDS image (linear copy):
  // chunk c: 16B unit (d, j) at byte d*128 + ((j*16) ^ ((d&7)<<4)),
  // holding W_enc[64c+8j+i][d], i=0..7.
  uint4* WbV = (uint4*)Wb;
  #pragma unroll
  for (int i = 0; i < 4; ++i) {
    const int u = t + 16384 * i;       // [0,65536)
    const int d = u & 511;
    const int j = (u >> 9) & 7;
    const int c = u >> 12;
    uint32_t h[8];
    #pragma unroll
    for (int kk = 0; kk < 8; ++kk) {
      float f = Watt[(size_t)(c * 64 + j * 8 + kk) * 512 + d];
      h[kk] = f32_to_bf16_rne(f);
    }
    uint4 val;
    val.x = h[0] | (h[1] << 16);
    val.y = h[2] | (h[3] << 16);
    val.z = h[4] | (h[5] << 16);
    val.w = h[6] | (h[7] << 16);
    const int unit = (d * 128 + ((j * 16) ^ ((d & 7) << 4))) >> 4;
    WbV[c * 4096 + unit] = val;
  }
}

// ---------------- Kernel B: fused energy GEMM + tanh + dot(v), v3 ----------------
// 512 blocks x 512 threads (8 waves, 2x4). BM=128, BN=512, BK=64.
// v3: raw s_barrier + COUNTED vmcnt (T4) — prefetches stay in flight across
// the barrier instead of __syncthreads' vmcnt(0) drain.
// Per-chunk schedule (1 barrier/chunk):
//   write A(c) from av          [compiler: counted wait for av only]
//   issue av(c+1)               [pre-barrier: regs, no shared hazard]
//   s_waitcnt vmcnt(4)          [drains B(c)'s 8 gload_lds; av(c+1) stays]
//   s_waitcnt lgkmcnt(0); s_barrier
//   issue B(c+1) gload_lds      [post-barrier: BL[(c+1)&1] aliases buffer
//                                read by compute(c-1); barrier(c) proves done]
//   compute(c)
// Safety: wave past barrier(c) => all waves finished compute(c-1) => all
// buffer overwrites race-free.
__global__ __launch_bounds__(512, 2) void energy_kernel(
    const float* __restrict__ x,       // (65536,1024)
    const uint16_t* __restrict__ Wb,   // swizzled bf16 chunks (1 MiB)
    const float* __restrict__ cbias,   // (32,512)
    const float* __restrict__ vvec,    // (512)
    float* __restrict__ att)           // (65536), pre-zeroed
{
  __shared__ __align__(16) uint8_t AL[2][128 * 128];   // 2 x 16 KB
  __shared__ __align__(16) uint8_t BL[2][512 * 128];   // 2 x 64 KB

  const int tid  = threadIdx.x;
  const int lane = tid & 63;
  const int wave = tid >> 6;
  const int wm   = wave >> 2;          // 0..1  (64-row group)
  const int wn   = wave & 3;           // 0..3  (128-col group)
  const int l15  = lane & 15;
  const int l4   = lane >> 4;
  const int brow0 = blockIdx.x * 128;
  const int b     = brow0 >> 11;

  // A staging map: 4 units/thread of 8B (4 bf16 from one float4)
  int aoff[4];
  const float* asrc[4];
  #pragma unroll
  for (int i = 0; i < 4; ++i) {
    const int idx = tid + 512 * i;     // [0,2048)
    const int r = idx >> 4, q = idx & 15;
    aoff[i] = r * 128 + ((q * 8) ^ ((r & 7) << 4));
    asrc[i] = x + (size_t)(brow0 + r) * 1024 + q * 4;
  }
  const uint8_t* wbase = (const uint8_t*)Wb + (lane << 4);

  f32x4 acc[4][8];
  #pragma unroll
  for (int mf = 0; mf < 4; ++mf)
    #pragma unroll
    for (int nf = 0; nf < 8; ++nf)
      acc[mf][nf] = (f32x4){0.f, 0.f, 0.f, 0.f};

  // prologue: issue av(0) FIRST (so waiting on it never drains B), then B(0)
  float4 av[4];
  #pragma unroll
  for (int i = 0; i < 4; ++i) av[i] = *(const float4*)(asrc[i]);
  #pragma unroll
  for (int i = 0; i < 8; ++i) {
    const int u = i * 8 + wave;
    __builtin_amdgcn_global_load_lds(
        (const __attribute__((address_space(1))) uint32_t*)(wbase + u * 1024),
        (__attribute__((address_space(3))) uint32_t*)(&BL[0][u * 1024]),
        16, 0, 0);
  }

  for (int c = 0; c < 16; ++c) {
    uint8_t* Ab = AL[c & 1];
    uint8_t* Bb = BL[c & 1];

    // write A(c) from av (compiler inserts counted vmcnt for av)
    #pragma unroll
    for (int i = 0; i < 4; ++i) {
      uint32_t lo = (uint32_t)f32_to_bf16_rne(av[i].x) | ((uint32_t)f32_to_bf16_rne(av[i].y) << 16);
      uint32_t hi = (uint32_t)f32_to_bf16_rne(av[i].z) | ((uint32_t)f32_to_bf16_rne(av[i].w) << 16);
      *(uint2*)(Ab + aoff[i]) = make_uint2(lo, hi);
    }

    if (c < 15) {
      // issue av(c+1) pre-barrier; stays in flight across it
      #pragma unroll
      for (int i = 0; i < 4; ++i) av[i] = *(const float4*)(asrc[i] + (c + 1) * 64);
      // drain ONLY B(c)'s 8 gload_lds (oldest); av(c+1)'s 4 remain in flight
      asm volatile("s_waitcnt vmcnt(4)" ::: "memory");
    } else {
      asm volatile("s_waitcnt vmcnt(0)" ::: "memory");
    }
    asm volatile("s_waitcnt lgkmcnt(0)" ::: "memory");  // A ds_writes visible
    __builtin_amdgcn_s_barrier();
    asm volatile("" ::: "memory");

    if (c < 15) {
      // issue B(c+1) post-barrier (safe to overwrite BL[(c+1)&1] now);
      // lands during compute(c) (~2500 cyc >> L2 latency)
      const uint8_t* wc = wbase + ((size_t)(c + 1) << 16);
      uint8_t* Bn = BL[(c + 1) & 1];
      #pragma unroll
      for (int i = 0; i < 8; ++i) {
        const int u = i * 8 + wave;
        __builtin_amdgcn_global_load_lds(
            (const __attribute__((address_space(1))) uint32_t*)(wc + u * 1024),
            (__attribute__((address_space(3))) uint32_t*)(Bn + u * 1024),
            16, 0, 0);
      }
    }

    // compute chunk c
    #pragma unroll
    for (int ks = 0; ks < 2; ++ks) {
      bf16x8 af[4], bfr[8];
      #pragma unroll
      for (int mf = 0; mf < 4; ++mf) {
        const int r = wm * 64 + mf * 16 + l15;
        af[mf] = *(const bf16x8*)(Ab + r * 128 + ((ks * 64 + l4 * 16) ^ ((r & 7) << 4)));
      }
      #pragma unroll
      for (int nf = 0; nf < 8; ++nf) {
        const int d = wn * 128 + nf * 16 + l15;
        bfr[nf] = *(const bf16x8*)(Bb + d * 128 + ((ks * 64 + l4 * 16) ^ ((d & 7) << 4)));
      }
      #pragma unroll
      for (int mf = 0; mf < 4; ++mf)
        #pragma unroll
        for (int nf = 0; nf < 8; ++nf)
          acc[mf][nf] = __builtin_amdgcn_mfma_f32_16x16x32_bf16(af[mf], bfr[nf], acc[mf][nf], 0, 0, 0);
    }
  }

  // epilogue: tanh + dot(v), 16-lane reduce, one atomic per (row, wn)
  float cb[8], vv[8];
  #pragma unroll
  for (int nf = 0; nf < 8; ++nf) {
    const int d = wn * 128 + nf * 16 + l15;
    cb[nf] = cbias[b * 512 + d];
    vv[nf] = vvec[d];
  }
  #pragma unroll
  for (int mf = 0; mf < 4; ++mf) {
    float s[4] = {0.f, 0.f, 0.f, 0.f};
    #pragma unroll
    for (int nf = 0; nf < 8; ++nf) {
      #pragma unroll
      for (int j = 0; j < 4; ++j) {
        const float e = acc[mf][nf][j] + cb[nf];
        s[j] += tanh_fast(e) * vv[nf];
      }
    }
    #pragma unroll
    for (int j = 0; j < 4; ++j) {
      float r = s[j];
      r += __shfl_xor(r, 1);
      r += __shfl_xor(r, 2);
      r += __shfl_xor(r, 4);
      r += __shfl_xor(r, 8);
      if (l15 == 0) atomicAdd(&att[brow0 + wm * 64 + mf * 16 + 4 * l4 + j], r);
    }
  }
}

// ---------------- Kernel C: softmax over S (in place) ----------------
__global__ __launch_bounds__(256) void softmax_kernel(float* __restrict__ att) {
  const int b = blockIdx.x;
  float* row = att + b * 2048;
  const int tid = threadIdx.x;
  __shared__ float redm[4], reds[4];

  float vals[8];
  float m = -1e30f;
  #pragma unroll
  for (int i = 0; i < 8; ++i) { vals[i] = row[tid + 256 * i]; m = fmaxf(m, vals[i]); }
  #pragma unroll
  for (int msk = 1; msk < 64; msk <<= 1) m = fmaxf(m, __shfl_xor(m, msk));
  if ((tid & 63) == 0) redm[tid >> 6] = m;
  __syncthreads();
  m = fmaxf(fmaxf(redm[0], redm[1]), fmaxf(redm[2], redm[3]));

  float s = 0.f;
  #pragma unroll
  for (int i = 0; i < 8; ++i) { vals[i] = __expf(vals[i] - m); s += vals[i]; }
  #pragma unroll
  for (int msk = 1; msk < 64; msk <<= 1) s += __shfl_xor(s, msk);
  if ((tid & 63) == 0) reds[tid >> 6] = s;
  __syncthreads();
  const float inv = 1.0f / (((reds[0] + reds[1]) + (reds[2] + reds[3])));
  #pragma unroll
  for (int i = 0; i < 8; ++i) row[tid + 256 * i] = vals[i] * inv;
}

// ---------------- Kernel D: context = w @ x ----------------
__global__ __launch_bounds__(256) void context_kernel(
    const float* __restrict__ x,   // (65536,1024)
    const float* __restrict__ w,   // (32,2048)
    float* __restrict__ out)       // (32,1024), pre-zeroed
{
  const int blk = blockIdx.x;
  const int b = blk >> 4, sc = blk & 15;
  const int tid = threadIdx.x;
  const float* xb = x + ((size_t)(b * 2048 + sc * 128)) * 1024 + tid * 4;
  const float* wb = w + b * 2048 + sc * 128;

  float4 acc = {0.f, 0.f, 0.f, 0.f};
  for (int si = 0; si < 128; ++si) {
    const float ww = wb[si];
    const float4 xv = *(const float4*)(xb + (size_t)si * 1024);
    acc.x += ww * xv.x;
    acc.y += ww * xv.y;
    acc.z += ww * xv.z;
    acc.w += ww * xv.w;
  }
  float* o = out + b * 1024 + tid * 4;
  atomicAdd(o + 0, acc.x);
  atomicAdd(o + 1, acc.y);
  atomicAdd(o + 2, acc.z);
  atomicAdd(o + 3, acc.w);
}

extern "C" void kernel_launch(void* const* d_in, const int* in_sizes, int n_in,
                              void* d_out, int out_size, void* d_ws, size_t ws_size,
                              hipStream_t stream) {
  const float* x    = (const float*)d_in[0];  // (32,2048,1024)
  const float* dec  = (const float*)d_in[1];  // (32,512)
  const float* Watt = (const float*)d_in[2];  // (1536,512)
  const float* batt = (const float*)d_in[3];  // (512)
  const float* v    = (const float*)d_in[4];  // (512)
  float* out = (float*)d_out;

  uint8_t* ws = (uint8_t*)d_ws;
  float*    att   = (float*)ws;                        // 256 KB
  float*    cbias = (float*)(ws + 256 * 1024);         // 64 KB
  uint16_t* Wb    = (uint16_t*)(ws + 320 * 1024);      // 1 MiB

  prep_kernel<<<64, 256, 0, stream>>>(dec, Watt, batt, att, cbias, Wb, out);
  energy_kernel<<<512, 512, 0, stream>>>(x, Wb, cbias, v, att);
  softmax_kernel<<<32, 256, 0, stream>>>(att);
  context_kernel<<<512, 256, 0, stream>>>(x, att, out);
}